// Round 9
// baseline (125.390 us; speedup 1.0000x reference)
//
#include <hip/hip_runtime.h>
#include <stdint.h>

#define W 768
#define NPROB (768*768)
#define NB 8
#define NBINS 2048           // 12-bit bins within the [0.5,1) binade
#define CAP 4096
#define TOPK 2048
#define SCORE_THR 0.6f
#define SUBS 32              // blocks per batch in stage1
#define PER4 (NPROB/4/SUBS)  // 4608 float4 per sub-block
#define RBLK 4               // rank blocks per batch in stage2 (1024 thr each)

#define MAGIC_H 0x4B1D0001u
#define MAGIC_S 0x4B1D0002u
#define MAGIC_R 0x4B1D0003u

// ws layout (bytes). cellmap needs NO init (validated r7/r8): poison/stale
// values >=2048 auto-fail `rank < r`; touched cells reset in fixout tail.
// Flags need NO init: consumers wait for ==MAGIC (poison != MAGIC); resets
// happen after all consumers (same kernel, or the following kernel).
#define MAP_OFF    0
#define MAP_BYTES  (NB*NPROB*2)                 // 9,437,184
#define HPART_OFF  (MAP_OFF + MAP_BYTES)
#define HPART_BYTES (NB*SUBS*NBINS*4)           // 2,097,152
#define META_OFF   (HPART_OFF + HPART_BYTES)
#define PFX_OFF    (META_OFF + 256)
#define PFX_BYTES  (NB*(NBINS+1)*4)
#define CUR_OFF    (PFX_OFF + PFX_BYTES)
#define CUR_BYTES  (NB*NBINS*4)
#define CAND_OFF   (CUR_OFF + CUR_BYTES)
#define CAND_BYTES (NB*CAP*8)
#define SKEY_OFF   (CAND_OFF + CAND_BYTES)
#define SKEY_BYTES (NB*TOPK*8)
#define FLAGH_OFF  (SKEY_OFF + SKEY_BYTES)
#define FLAGH_BYTES (NB*SUBS*4)                 // 1,024
#define FLAGS_OFF  (FLAGH_OFF + FLAGH_BYTES)
#define FLAGS_BYTES (NB*16*4)                   // select flag, stride 16 u32
#define FLAGR_OFF  (FLAGS_OFF + FLAGS_BYTES)
#define FLAGR_BYTES (NB*16*4)                   // rank flags, [b*16+p]
#define WS_TOTAL   (FLAGR_OFF + FLAGR_BYTES)

struct Meta { unsigned bstar; unsigned cnt; unsigned pad0; unsigned pad1; };

// valid scores in [0.6,1.0) -> exponent-126 binade; bits monotone.
__device__ __forceinline__ unsigned score_bin(unsigned fb) {
    return (fb >> 12) & 0x7FFu;
}

__device__ __forceinline__ void flag_store(unsigned* p, unsigned v) {
    __hip_atomic_store(p, v, __ATOMIC_RELEASE, __HIP_MEMORY_SCOPE_AGENT);
}
__device__ __forceinline__ unsigned flag_load(unsigned* p) {
    return __hip_atomic_load(p, __ATOMIC_ACQUIRE, __HIP_MEMORY_SCOPE_AGENT);
}

// K1: hist -> (designated block) select -> (all blocks) compact.
__global__ __launch_bounds__(256) void stage1_kernel(
    const float* __restrict__ probs, unsigned* __restrict__ hpart,
    Meta* __restrict__ meta, unsigned* __restrict__ binpfx,
    unsigned* __restrict__ cursor, unsigned long long* __restrict__ cand,
    unsigned* __restrict__ flagh, unsigned* __restrict__ flagsel)
{
    __shared__ unsigned lh[NBINS];
    __shared__ unsigned h[NBINS];
    __shared__ unsigned pfx[NBINS + 1];
    __shared__ unsigned csum[256];
    __shared__ unsigned sb;
    const int b = blockIdx.y, hs = blockIdx.x, tid = threadIdx.x;

    // ---- hist ----
    for (int i = tid; i < NBINS; i += 256) lh[i] = 0;
    __syncthreads();
    const float4* p = (const float4*)(probs + (size_t)b * NPROB) + (size_t)hs * PER4;
    for (int i = tid; i < PER4; i += 256) {
        float4 v = p[i];
        if (v.x >= SCORE_THR) atomicAdd(&lh[score_bin(__float_as_uint(v.x))], 1u);
        if (v.y >= SCORE_THR) atomicAdd(&lh[score_bin(__float_as_uint(v.y))], 1u);
        if (v.z >= SCORE_THR) atomicAdd(&lh[score_bin(__float_as_uint(v.z))], 1u);
        if (v.w >= SCORE_THR) atomicAdd(&lh[score_bin(__float_as_uint(v.w))], 1u);
    }
    __syncthreads();
    {
        unsigned* gh = hpart + (size_t)(b * SUBS + hs) * NBINS;
        for (int i = tid; i < NBINS; i += 256) gh[i] = lh[i];
    }
    __syncthreads();
    if (tid == 0) { __threadfence(); flag_store(&flagh[b * SUBS + hs], MAGIC_H); }

    // ---- select (designated block per batch) ----
    if (hs == SUBS - 1) {
        if (tid < SUBS - 1) {
            while (flag_load(&flagh[b * SUBS + tid]) != MAGIC_H)
                __builtin_amdgcn_s_sleep(2);
        }
        __syncthreads();
        for (int i = tid; i < NBINS; i += 256) {
            unsigned s = 0;
            const unsigned* hp = hpart + (size_t)b * SUBS * NBINS + i;
            #pragma unroll 8
            for (int pp = 0; pp < SUBS; ++pp) s += hp[(size_t)pp * NBINS];
            h[i] = s;
        }
        if (tid == 0) sb = 0;
        __syncthreads();
        unsigned s = 0;
        #pragma unroll
        for (int i = 0; i < 8; ++i) s += h[tid * 8 + i];
        csum[tid] = s;
        __syncthreads();
        for (int off = 1; off < 256; off <<= 1) {
            unsigned v = (tid + off < 256) ? csum[tid + off] : 0u;
            __syncthreads();
            csum[tid] += v;
            __syncthreads();
        }
        unsigned run = csum[tid];           // sum over bins >= 8*tid
        #pragma unroll
        for (int i = 0; i < 8; ++i) { pfx[tid * 8 + i] = run; run -= h[tid * 8 + i]; }
        if (tid == 0) pfx[NBINS] = 0;
        __syncthreads();
        #pragma unroll
        for (int i = 0; i < 8; ++i) {
            int B = tid * 8 + i;
            if (pfx[B] >= TOPK && pfx[B + 1] < TOPK) sb = (unsigned)B;  // unique writer
        }
        __syncthreads();
        if (tid == 0) {
            unsigned bs = sb;
            unsigned n = pfx[bs];
            meta[b].bstar = bs;
            meta[b].cnt = n < CAP ? n : CAP;
        }
        for (int i = tid; i < NBINS; i += 256) {
            binpfx[b * (NBINS + 1) + i] = pfx[i];
            cursor[b * NBINS + i] = pfx[i + 1];   // bin segment start
        }
        if (tid == 0) binpfx[b * (NBINS + 1) + NBINS] = 0;
        if (tid < SUBS) flagh[b * SUBS + tid] = 0;   // reset for next replay
        __syncthreads();
        if (tid == 0) { __threadfence(); flag_store(&flagsel[b * 16], MAGIC_S); }
    }

    // ---- wait for select, then compact ----
    if (tid == 0) {
        while (flag_load(&flagsel[b * 16]) != MAGIC_S)
            __builtin_amdgcn_s_sleep(2);
    }
    __syncthreads();

    unsigned bstar = meta[b].bstar;
    int base_elem = hs * PER4 * 4;
    unsigned long long* dst = cand + (size_t)b * CAP;
    for (int i = tid; i < PER4; i += 256) {
        float4 v = p[i];
        int ei = base_elem + i * 4;
        float sv[4] = {v.x, v.y, v.z, v.w};
        #pragma unroll
        for (int c = 0; c < 4; ++c) {
            float s2 = sv[c];
            if (s2 >= SCORE_THR) {
                unsigned fb = __float_as_uint(s2);
                unsigned B = score_bin(fb);
                if (B >= bstar) {
                    unsigned pos = atomicAdd(&cursor[b * NBINS + B], 1u);
                    if (pos < CAP) {
                        unsigned idx = (unsigned)(ei + c);
                        dst[pos] = ((unsigned long long)fb << 32) | (unsigned)(~idx);
                    }
                }
            }
        }
    }
}

// K2: rank (4 blocks/batch) -> (designated block) fixpoint NMS + refine + out.
__global__ __launch_bounds__(1024) void rankfix_kernel(
    const float* __restrict__ dev4, const unsigned long long* __restrict__ cand,
    const Meta* __restrict__ meta, const unsigned* __restrict__ binpfx,
    unsigned long long* __restrict__ skey, unsigned short* __restrict__ cellmap,
    float* __restrict__ out, unsigned* __restrict__ flagr, unsigned* __restrict__ flagsel)
{
    __shared__ unsigned k32[CAP];             // 16 KB
    __shared__ unsigned s_pfx[NBINS + 1];     // 8.2 KB
    __shared__ unsigned char s_state[TOPK];   // 2 KB
    __shared__ int s_changed;
    const int b = blockIdx.y, pp = blockIdx.x, tid = threadIdx.x;

    if (pp == 0 && tid == 0) flagsel[b * 16] = 0;   // reset K1 select flag for next replay

    int n = (int)meta[b].cnt;                 // <= CAP
    int nload = (n + 1023) & ~1023;
    if (nload > CAP) nload = CAP;
    for (int i = tid; i < nload; i += 1024) {
        unsigned long long key = cand[(size_t)b * CAP + i];
        unsigned fb = (unsigned)(key >> 32);
        k32[i] = ((fb & 0xFFFu) << 20) | ((unsigned)key & 0xFFFFFu);  // (u32)key == ~idx
    }
    for (int i = tid; i <= NBINS; i += 1024) s_pfx[i] = binpfx[b * (NBINS + 1) + i];
    __syncthreads();

    // rank candidate (pp*1024 + tid) within its bin segment
    {
        int q = pp * 1024 + tid;
        if (q < n) {
            unsigned long long key = cand[(size_t)b * CAP + q];
            unsigned fb = (unsigned)(key >> 32);
            unsigned idx = ~(unsigned)key;
            unsigned B = score_bin(fb);
            unsigned my = k32[q];
            int st = (int)s_pfx[B + 1];
            int en = (int)s_pfx[B]; if (en > n) en = n;
            int r = st;
            for (int i = st; i < en; ++i) r += (k32[i] > my);
            if (r < TOPK) {
                skey[(size_t)b * TOPK + r] = key;
                cellmap[(size_t)b * NPROB + idx] = (unsigned short)r;
            }
        }
    }
    __syncthreads();
    if (tid == 0) { __threadfence(); flag_store(&flagr[b * 16 + pp], MAGIC_R); }
    if (pp != RBLK - 1) return;

    // ---- designated block: wait peers, fixpoint NMS, refine + out + cleanup ----
    if (tid < RBLK) {
        while (flag_load(&flagr[b * 16 + tid]) != MAGIC_R)
            __builtin_amdgcn_s_sleep(2);
    }
    __syncthreads();
    if (tid < RBLK) flagr[b * 16 + tid] = 0;   // reset for next replay

    int nvalid = n < TOPK ? n : TOPK;
    unsigned short* cm = cellmap + (size_t)b * NPROB;
    constexpr int DYv[8] = {-1,-1,-1, 0, 0, 1, 1, 1};
    constexpr int DXv[8] = {-1, 0, 1,-1, 1,-1, 0, 1};
    unsigned long long mykey[2];
    unsigned myidx[2];
    unsigned long long l0[2] = {0,0}, l1[2] = {0,0};
    int nc[2] = {0,0};
    bool vld[2];

    #pragma unroll 2
    for (int q = 0; q < 2; ++q) {
        int r = tid + q * 1024;
        vld[q] = (r < nvalid);
        mykey[q] = 0; myidx[q] = 0;
        unsigned char stinit = 2;
        if (vld[q]) {
            unsigned long long key = skey[(size_t)b * TOPK + r];
            mykey[q] = key;
            unsigned idx = ~(unsigned)key;
            myidx[q] = idx;
            int y = (int)(idx / W), x = (int)(idx % W);
            int c2 = 0;
            unsigned long long a0 = 0, a1 = 0;
            #pragma unroll
            for (int t8 = 0; t8 < 8; ++t8) {
                int ny = y + DYv[t8], nx = x + DXv[t8];
                if ((unsigned)ny < (unsigned)W && (unsigned)nx < (unsigned)W) {
                    unsigned rr = cm[ny * W + nx];
                    if (rr < (unsigned)r) {      // stale/poison (>=2048) auto-fails
                        if (c2 < 4) a0 |= (unsigned long long)rr << (c2 * 16);
                        else        a1 |= (unsigned long long)rr << ((c2 - 4) * 16);
                        c2++;
                    }
                }
            }
            l0[q] = a0; l1[q] = a1; nc[q] = c2;
            stinit = (c2 == 0) ? 1 : 0;
        }
        s_state[r] = stinit;
    }
    __syncthreads();

    while (true) {
        if (tid == 0) s_changed = 0;
        __syncthreads();
        bool ch = false;
        #pragma unroll 2
        for (int q = 0; q < 2; ++q) {
            int r = tid + q * 1024;
            if (nc[q] > 0 && s_state[r] == 0) {
                bool anyK = false, anyU = false;
                int c = nc[q];
                #pragma unroll
                for (int l = 0; l < 8; ++l) {
                    if (l < c) {
                        unsigned rr = (l < 4)
                            ? (unsigned)((l0[q] >> (l * 16)) & 0xFFFFu)
                            : (unsigned)((l1[q] >> ((l - 4) * 16)) & 0xFFFFu);
                        unsigned char st = s_state[rr];
                        anyK |= (st == 1);
                        anyU |= (st == 0);
                    }
                }
                if (anyK)      { s_state[r] = 2; ch = true; }
                else if (!anyU){ s_state[r] = 1; ch = true; }
            }
        }
        if (ch) s_changed = 1;
        __syncthreads();
        if (s_changed == 0) break;
        __syncthreads();
    }

    #pragma unroll 2
    for (int q = 0; q < 2; ++q) {
        int r = tid + q * 1024;
        float o0 = 0.f, o1 = 0.f, o2 = 0.f, o3 = 0.f, o4 = 0.f;
        if (vld[q] && s_state[r] == 1) {
            unsigned idx = myidx[q];
            float sc = __uint_as_float((unsigned)(mykey[q] >> 32));
            int y = (int)(idx / W), x = (int)(idx % W);
            const float4 d = ((const float4*)dev4)[(size_t)b * NPROB + idx];
            float b0 = (float)(4 * y + 2);
            float b1 = (float)(4 * x + 2);
            float b2 = (float)(4 * y + 24);
            float b3 = (float)(4 * x + 24);
            float r0 = b0 + d.x * 22.0f;
            float r1 = b1 + d.y * 22.0f;
            float r2 = b2 + d.z * 22.0f;
            float r3 = b3 + d.w * 22.0f;
            float rh = r2 - r0, rw = r3 - r1;
            float len = fmaxf(rh, rw);
            float c0 = r0 + rh * 0.5f, c1v = r1 + rw * 0.5f;
            float u0 = c0 - 0.5f * len, u1 = c1v - 0.5f * len;
            float v0 = u0 + len, v1 = u1 + len;
            o0 = fminf(fmaxf(u0, 1.0f), 3095.0f);
            o1 = fminf(fmaxf(u1, 1.0f), 3095.0f);
            o2 = fminf(fmaxf(v0, 1.0f), 3095.0f);
            o3 = fminf(fmaxf(v1, 1.0f), 3095.0f);
            o4 = sc;
        }
        float* op = out + ((size_t)b * TOPK + r) * 5;
        op[0] = o0; op[1] = o1; op[2] = o2; op[3] = o3; op[4] = o4;
        if (vld[q]) cm[myidx[q]] = 0xFFFFu;   // reset touched cells for next replay
    }
}

extern "C" void kernel_launch(void* const* d_in, const int* in_sizes, int n_in,
                              void* d_out, int out_size, void* d_ws, size_t ws_size,
                              hipStream_t stream) {
    (void)in_sizes; (void)n_in; (void)out_size;
    if (ws_size < (size_t)WS_TOTAL) return;

    const float* probs = (const float*)d_in[0];
    const float* devs  = (const float*)d_in[1];
    float* out = (float*)d_out;
    char* ws = (char*)d_ws;

    unsigned short* cellmap = (unsigned short*)(ws + MAP_OFF);
    unsigned* hpart = (unsigned*)(ws + HPART_OFF);
    Meta* meta = (Meta*)(ws + META_OFF);
    unsigned* binpfx = (unsigned*)(ws + PFX_OFF);
    unsigned* cursor = (unsigned*)(ws + CUR_OFF);
    unsigned long long* cand = (unsigned long long*)(ws + CAND_OFF);
    unsigned long long* skey = (unsigned long long*)(ws + SKEY_OFF);
    unsigned* flagh = (unsigned*)(ws + FLAGH_OFF);
    unsigned* flagsel = (unsigned*)(ws + FLAGS_OFF);
    unsigned* flagr = (unsigned*)(ws + FLAGR_OFF);

    stage1_kernel<<<dim3(SUBS, NB), 256, 0, stream>>>(probs, hpart, meta, binpfx,
                                                      cursor, cand, flagh, flagsel);
    rankfix_kernel<<<dim3(RBLK, NB), 1024, 0, stream>>>(devs, cand, meta, binpfx,
                                                        skey, cellmap, out, flagr, flagsel);
}

// Round 10
// 80.616 us; speedup vs baseline: 1.5554x; 1.5554x over previous
//
#include <hip/hip_runtime.h>
#include <stdint.h>

#define W 768
#define NPROB (768*768)
#define NB 8
#define NBINS 2048           // bin = (fb>>12)&0x7FF within the [0.5,1) binade
#define CAP 4096
#define TOPK 2048
#define SCORE_THR 0.6f
#define SUBS 32              // K1 blocks per batch
#define SEG (NPROB/SUBS)     // 18432 elems per K1 block
#define PER4 (SEG/4)         // 4608 float4 per K1 block

// ws layout (bytes). NOTHING needs pre-init:
//  - bucket/hpart: written by K1 before K2 reads (stream order)
//  - cellmap: poison/stale >=2048 auto-fails `rank < r` (validated r7/r8);
//    touched cells reset in K2 tail -> deterministic replays
#define MAP_OFF    0
#define MAP_BYTES  (NB*NPROB*2)                 // 9,437,184
#define HPART_OFF  (MAP_OFF + MAP_BYTES)
#define HPART_BYTES (NB*SUBS*NBINS*2)           // 1,048,576 (u16 packed as u32 pairs)
#define BUCKET_OFF (HPART_OFF + HPART_BYTES)
#define BUCKET_BYTES (NB*(size_t)SUBS*SEG*8)    // 37,748,736
#define WS_TOTAL   (BUCKET_OFF + BUCKET_BYTES)

// valid scores in [0.6,1.0) -> exponent-126 binade; float bits monotone.
__device__ __forceinline__ unsigned score_bin(unsigned fb) {
    return (fb >> 12) & 0x7FFu;
}

// K1: per-block counting sort. LDS hist -> packed partial hist out;
// LDS descending-suffix cursors -> scatter candidates (u64 keys) into this
// block's private bucket segment, ordered by DESCENDING bin. No global
// atomics, no init, no overflow (segment size == chunk size).
__global__ __launch_bounds__(256) void scatter_kernel(
    const float* __restrict__ probs, unsigned* __restrict__ hpart32,
    unsigned long long* __restrict__ bucket)
{
    __shared__ unsigned lh[NBINS];     // 8 KB
    __shared__ unsigned cur[NBINS];    // 8 KB
    __shared__ unsigned csum[256];     // 1 KB
    const int b = blockIdx.y, hs = blockIdx.x, tid = threadIdx.x;

    for (int i = tid; i < NBINS; i += 256) lh[i] = 0;
    __syncthreads();
    const float4* p = (const float4*)(probs + (size_t)b * NPROB) + (size_t)hs * PER4;
    for (int i = tid; i < PER4; i += 256) {
        float4 v = p[i];
        if (v.x >= SCORE_THR) atomicAdd(&lh[score_bin(__float_as_uint(v.x))], 1u);
        if (v.y >= SCORE_THR) atomicAdd(&lh[score_bin(__float_as_uint(v.y))], 1u);
        if (v.z >= SCORE_THR) atomicAdd(&lh[score_bin(__float_as_uint(v.z))], 1u);
        if (v.w >= SCORE_THR) atomicAdd(&lh[score_bin(__float_as_uint(v.w))], 1u);
    }
    __syncthreads();
    // packed partial hist (counts <= 18432 fit u16)
    {
        unsigned* gh = hpart32 + (size_t)(b * SUBS + hs) * (NBINS / 2);
        for (int i = tid; i < NBINS / 2; i += 256)
            gh[i] = (lh[2 * i] & 0xFFFFu) | (lh[2 * i + 1] << 16);
    }
    // descending-suffix cursors: cur[B] = #{cands with bin > B}
    unsigned s = 0;
    #pragma unroll
    for (int i = 0; i < 8; ++i) s += lh[tid * 8 + i];
    csum[tid] = s;
    __syncthreads();
    for (int off = 1; off < 256; off <<= 1) {
        unsigned v = (tid + off < 256) ? csum[tid + off] : 0u;
        __syncthreads();
        csum[tid] += v;
        __syncthreads();
    }
    unsigned run = csum[tid];               // = sum over bins >= 8*tid
    #pragma unroll
    for (int i = 0; i < 8; ++i) { cur[tid * 8 + i] = run - lh[tid * 8 + i]; run -= lh[tid * 8 + i]; }
    __syncthreads();
    // pass 2: scatter (chunk re-read hits L1/L2)
    unsigned long long* dst = bucket + (size_t)(b * SUBS + hs) * SEG;
    int base_elem = hs * SEG;
    for (int i = tid; i < PER4; i += 256) {
        float4 v = p[i];
        int ei = base_elem + i * 4;
        float sv[4] = {v.x, v.y, v.z, v.w};
        #pragma unroll
        for (int c = 0; c < 4; ++c) {
            float s2 = sv[c];
            if (s2 >= SCORE_THR) {
                unsigned fb = __float_as_uint(s2);
                unsigned B = score_bin(fb);
                unsigned pos = atomicAdd(&cur[B], 1u);    // LDS cursor
                unsigned idx = (unsigned)(ei + c);
                dst[pos] = ((unsigned long long)fb << 32) | (unsigned)(~idx);
            }
        }
    }
}

// K2: one block per batch. Reduce partial hists -> suffix pfx -> bstar;
// per-source-block prefix sizes (bins>=bstar are a prefix of each sorted
// segment) -> gather -> LDS counting-sort by bin -> exact in-bin rank ->
// cellmap -> fixpoint NMS -> refine + out + cleanup.
__global__ __launch_bounds__(1024) void finish_kernel(
    const float* __restrict__ dev4, const unsigned* __restrict__ hpart32,
    const unsigned long long* __restrict__ bucket,
    unsigned short* __restrict__ cellmap, float* __restrict__ out)
{
    __shared__ unsigned gpfx[NBINS + 1];        // 8.2 KB  suffix-inclusive counts
    __shared__ unsigned cur[NBINS];             // 8 KB    counting-sort cursors
    __shared__ unsigned csum[1024];             // 4 KB
    __shared__ unsigned long long keys2[CAP];   // 32 KB   bin-grouped keys
    __shared__ unsigned char s_state[TOPK];     // 2 KB
    __shared__ unsigned sj[SUBS];
    __shared__ unsigned basej[SUBS + 1];
    __shared__ unsigned sbstar;
    __shared__ int s_changed;
    const int b = blockIdx.x, tid = threadIdx.x;

    // ---- reduce 32 partial hists; thread t owns bins 2t, 2t+1 ----
    unsigned c0 = 0, c1 = 0;
    for (int j = 0; j < SUBS; ++j) {
        unsigned pr = hpart32[(size_t)(b * SUBS + j) * (NBINS / 2) + tid];
        c0 += pr & 0xFFFFu;
        c1 += pr >> 16;
    }
    csum[tid] = c0 + c1;
    if (tid == 0) sbstar = 0;
    __syncthreads();
    for (int off = 1; off < 1024; off <<= 1) {
        unsigned v = (tid + off < 1024) ? csum[tid + off] : 0u;
        __syncthreads();
        csum[tid] += v;
        __syncthreads();
    }
    gpfx[2 * tid] = csum[tid];                 // = count bins >= 2t
    gpfx[2 * tid + 1] = csum[tid] - c0;
    if (tid == 0) gpfx[NBINS] = 0;
    __syncthreads();
    {
        int B0 = 2 * tid, B1 = 2 * tid + 1;
        if (gpfx[B0] >= TOPK && gpfx[B0 + 1] < TOPK) sbstar = (unsigned)B0;
        if (gpfx[B1] >= TOPK && gpfx[B1 + 1] < TOPK) sbstar = (unsigned)B1;
    }
    __syncthreads();
    const unsigned bstar = sbstar;
    const unsigned Tfull = gpfx[bstar];
    const unsigned T = Tfull < CAP ? Tfull : CAP;
    const int nvalid = (int)(T < TOPK ? T : TOPK);

    // ---- per-source-block prefix sizes: sj[j] = #{bins >= bstar} in block j ----
    {
        int j = tid >> 5, lane = tid & 31;
        unsigned s = 0;
        for (unsigned B = bstar + lane; B < NBINS; B += 32)
            s += gpfx[B] - gpfx[B + 1];       // == h[B]... per-batch; need per-block!
        (void)s;
    }
    // NOTE: sj must come from the PER-BLOCK hists, not the batch hist:
    {
        int j = tid >> 5, lane = tid & 31;
        unsigned s = 0;
        const unsigned* hp = hpart32 + (size_t)(b * SUBS + j) * (NBINS / 2);
        // walk packed pairs covering bins >= bstar
        for (unsigned pi = (bstar >> 1) + lane; pi < NBINS / 2; pi += 32) {
            unsigned pr = hp[pi];
            unsigned lo = pr & 0xFFFFu, hi = pr >> 16;
            unsigned binlo = 2 * pi;
            s += (binlo >= bstar ? lo : 0u) + hi;   // bin 2pi+1 >= bstar always here
        }
        #pragma unroll
        for (int d = 16; d > 0; d >>= 1) s += __shfl_down(s, d, 32);
        if (lane == 0) sj[j] = s;
    }
    __syncthreads();
    if (tid == 0) {
        unsigned acc = 0;
        for (int j = 0; j < SUBS; ++j) { basej[j] = acc; acc += sj[j]; }
        basej[SUBS] = acc;
    }
    for (unsigned B = bstar + tid; B < NBINS; B += 1024) cur[B] = gpfx[B + 1];
    __syncthreads();

    // ---- gather prefixes, scatter into bin-grouped keys2 ----
    for (unsigned i = tid; i < T; i += 1024) {
        int lo = 0, hi = SUBS - 1;
        while (lo < hi) { int mid = (lo + hi + 1) >> 1; if (basej[mid] <= i) lo = mid; else hi = mid - 1; }
        unsigned long long key = bucket[(size_t)(b * SUBS + lo) * SEG + (i - basej[lo])];
        unsigned B = (unsigned)(key >> 44) & 0x7FFu;
        unsigned pos = atomicAdd(&cur[B], 1u);
        if (pos < CAP) keys2[pos] = key;
    }
    __syncthreads();

    // ---- exact rank per owned entry; write cellmap ----
    unsigned myr[4];
    unsigned long long mykey[4];
    unsigned myidx[4];
    unsigned short* cm = cellmap + (size_t)b * NPROB;
    #pragma unroll
    for (int q = 0; q < 4; ++q) {
        unsigned pos = tid + q * 1024;
        myr[q] = 0xFFFFFFFFu;
        if (pos < T) {
            unsigned long long key = keys2[pos];
            unsigned B = (unsigned)(key >> 44) & 0x7FFu;
            unsigned st = gpfx[B + 1];
            unsigned en = gpfx[B]; if (en > T) en = T;
            unsigned r = st;
            for (unsigned i = st; i < en; ++i) r += (keys2[i] > key);
            if (r < (unsigned)nvalid) {
                myr[q] = r;
                mykey[q] = key;
                unsigned idx = ~(unsigned)key;
                myidx[q] = idx;
                cm[idx] = (unsigned short)r;
            }
        }
    }
    for (int i = tid; i < TOPK; i += 1024) s_state[i] = 2;
    __threadfence_block();
    __syncthreads();

    // ---- neighbor discovery (8 cellmap probes; stale/poison >=2048 auto-fails) ----
    constexpr int DYv[8] = {-1,-1,-1, 0, 0, 1, 1, 1};
    constexpr int DXv[8] = {-1, 0, 1,-1, 1,-1, 0, 1};
    unsigned long long l0[4] = {0,0,0,0}, l1[4] = {0,0,0,0};
    int nc[4] = {0,0,0,0};
    #pragma unroll
    for (int q = 0; q < 4; ++q) {
        if (myr[q] != 0xFFFFFFFFu) {
            unsigned idx = myidx[q];
            int y = (int)(idx / W), x = (int)(idx % W);
            int c2 = 0;
            unsigned long long a0 = 0, a1 = 0;
            #pragma unroll
            for (int t8 = 0; t8 < 8; ++t8) {
                int ny = y + DYv[t8], nx = x + DXv[t8];
                if ((unsigned)ny < (unsigned)W && (unsigned)nx < (unsigned)W) {
                    unsigned rr = cm[ny * W + nx];
                    if (rr < myr[q]) {
                        if (c2 < 4) a0 |= (unsigned long long)rr << (c2 * 16);
                        else        a1 |= (unsigned long long)rr << ((c2 - 4) * 16);
                        c2++;
                    }
                }
            }
            l0[q] = a0; l1[q] = a1; nc[q] = c2;
            s_state[myr[q]] = (c2 == 0) ? 1 : 0;
        }
    }
    __syncthreads();

    // ---- monotone fixpoint == sequential greedy NMS ----
    while (true) {
        if (tid == 0) s_changed = 0;
        __syncthreads();
        bool ch = false;
        #pragma unroll
        for (int q = 0; q < 4; ++q) {
            if (myr[q] != 0xFFFFFFFFu && s_state[myr[q]] == 0) {
                bool anyK = false, anyU = false;
                int c = nc[q];
                #pragma unroll
                for (int l = 0; l < 8; ++l) {
                    if (l < c) {
                        unsigned rr = (l < 4)
                            ? (unsigned)((l0[q] >> (l * 16)) & 0xFFFFu)
                            : (unsigned)((l1[q] >> ((l - 4) * 16)) & 0xFFFFu);
                        unsigned char st = s_state[rr];
                        anyK |= (st == 1);
                        anyU |= (st == 0);
                    }
                }
                if (anyK)      { s_state[myr[q]] = 2; ch = true; }
                else if (!anyU){ s_state[myr[q]] = 1; ch = true; }
            }
        }
        if (ch) s_changed = 1;
        __syncthreads();
        if (s_changed == 0) break;
        __syncthreads();
    }

    // ---- refine + write + cleanup ----
    for (int r = nvalid + tid; r < TOPK; r += 1024) {
        float* op = out + ((size_t)b * TOPK + r) * 5;
        op[0] = 0.f; op[1] = 0.f; op[2] = 0.f; op[3] = 0.f; op[4] = 0.f;
    }
    #pragma unroll
    for (int q = 0; q < 4; ++q) {
        if (myr[q] != 0xFFFFFFFFu) {
            unsigned r = myr[q];
            float o0 = 0.f, o1 = 0.f, o2 = 0.f, o3 = 0.f, o4 = 0.f;
            if (s_state[r] == 1) {
                unsigned idx = myidx[q];
                float sc = __uint_as_float((unsigned)(mykey[q] >> 32));
                int y = (int)(idx / W), x = (int)(idx % W);
                const float4 d = ((const float4*)dev4)[(size_t)b * NPROB + idx];
                float b0 = (float)(4 * y + 2);
                float b1 = (float)(4 * x + 2);
                float b2 = (float)(4 * y + 24);
                float b3 = (float)(4 * x + 24);
                float r0 = b0 + d.x * 22.0f;
                float r1 = b1 + d.y * 22.0f;
                float r2 = b2 + d.z * 22.0f;
                float r3 = b3 + d.w * 22.0f;
                float rh = r2 - r0, rw = r3 - r1;
                float len = fmaxf(rh, rw);
                float c0v = r0 + rh * 0.5f, c1v = r1 + rw * 0.5f;
                float u0 = c0v - 0.5f * len, u1 = c1v - 0.5f * len;
                float v0 = u0 + len, v1 = u1 + len;
                o0 = fminf(fmaxf(u0, 1.0f), 3095.0f);
                o1 = fminf(fmaxf(u1, 1.0f), 3095.0f);
                o2 = fminf(fmaxf(v0, 1.0f), 3095.0f);
                o3 = fminf(fmaxf(v1, 1.0f), 3095.0f);
                o4 = sc;
            }
            float* op = out + ((size_t)b * TOPK + r) * 5;
            op[0] = o0; op[1] = o1; op[2] = o2; op[3] = o3; op[4] = o4;
            cm[myidx[q]] = 0xFFFFu;   // reset touched cell for next replay
        }
    }
}

extern "C" void kernel_launch(void* const* d_in, const int* in_sizes, int n_in,
                              void* d_out, int out_size, void* d_ws, size_t ws_size,
                              hipStream_t stream) {
    (void)in_sizes; (void)n_in; (void)out_size;
    if (ws_size < (size_t)WS_TOTAL) return;

    const float* probs = (const float*)d_in[0];
    const float* devs  = (const float*)d_in[1];
    float* out = (float*)d_out;
    char* ws = (char*)d_ws;

    unsigned short* cellmap = (unsigned short*)(ws + MAP_OFF);
    unsigned* hpart32 = (unsigned*)(ws + HPART_OFF);
    unsigned long long* bucket = (unsigned long long*)(ws + BUCKET_OFF);

    scatter_kernel<<<dim3(SUBS, NB), 256, 0, stream>>>(probs, hpart32, bucket);
    finish_kernel<<<NB, 1024, 0, stream>>>(devs, hpart32, bucket, cellmap, out);
}

// Round 11
// 48.653 us; speedup vs baseline: 2.5772x; 1.6570x over previous
//
#include <hip/hip_runtime.h>
#include <stdint.h>

#define W 768
#define NPROB (768*768)
#define NB 8
#define NBINS 2048           // coarse bin = (fb>>12)&0x7FF within the [0.5,1) binade
#define CAP 4096
#define TOPK 2048
#define SCORE_THR 0.6f
#define SUBS 32              // K1 blocks per batch
#define SEG (NPROB/SUBS)     // 18432 elems per K1 block
#define PER4 (SEG/4)         // 4608 float4 per K1 block

// ws layout (bytes). NOTHING needs pre-init: bucket/hpart written by K1
// before K2 reads (stream order). No cellmap anymore.
#define HPART_OFF  0
#define HPART_BYTES (NB*SUBS*NBINS*2)           // 1,048,576 (u16 pairs in u32)
#define BUCKET_OFF (HPART_OFF + HPART_BYTES)
#define BUCKET_BYTES (NB*(size_t)SUBS*SEG*8)    // 37,748,736
#define WS_TOTAL   (BUCKET_OFF + BUCKET_BYTES)

// valid scores in [0.6,1.0) -> exponent-126 binade; float bits monotone.
__device__ __forceinline__ unsigned score_bin(unsigned fb) {
    return (fb >> 12) & 0x7FFu;
}

// K1: per-block counting sort (unchanged from r10 — verified).
__global__ __launch_bounds__(256) void scatter_kernel(
    const float* __restrict__ probs, unsigned* __restrict__ hpart32,
    unsigned long long* __restrict__ bucket)
{
    __shared__ unsigned lh[NBINS];
    __shared__ unsigned cur[NBINS];
    __shared__ unsigned csum[256];
    const int b = blockIdx.y, hs = blockIdx.x, tid = threadIdx.x;

    for (int i = tid; i < NBINS; i += 256) lh[i] = 0;
    __syncthreads();
    const float4* p = (const float4*)(probs + (size_t)b * NPROB) + (size_t)hs * PER4;
    for (int i = tid; i < PER4; i += 256) {
        float4 v = p[i];
        if (v.x >= SCORE_THR) atomicAdd(&lh[score_bin(__float_as_uint(v.x))], 1u);
        if (v.y >= SCORE_THR) atomicAdd(&lh[score_bin(__float_as_uint(v.y))], 1u);
        if (v.z >= SCORE_THR) atomicAdd(&lh[score_bin(__float_as_uint(v.z))], 1u);
        if (v.w >= SCORE_THR) atomicAdd(&lh[score_bin(__float_as_uint(v.w))], 1u);
    }
    __syncthreads();
    {
        unsigned* gh = hpart32 + (size_t)(b * SUBS + hs) * (NBINS / 2);
        for (int i = tid; i < NBINS / 2; i += 256)
            gh[i] = (lh[2 * i] & 0xFFFFu) | (lh[2 * i + 1] << 16);
    }
    unsigned s = 0;
    #pragma unroll
    for (int i = 0; i < 8; ++i) s += lh[tid * 8 + i];
    csum[tid] = s;
    __syncthreads();
    for (int off = 1; off < 256; off <<= 1) {
        unsigned v = (tid + off < 256) ? csum[tid + off] : 0u;
        __syncthreads();
        csum[tid] += v;
        __syncthreads();
    }
    unsigned run = csum[tid];
    #pragma unroll
    for (int i = 0; i < 8; ++i) { cur[tid * 8 + i] = run - lh[tid * 8 + i]; run -= lh[tid * 8 + i]; }
    __syncthreads();
    unsigned long long* dst = bucket + (size_t)(b * SUBS + hs) * SEG;
    int base_elem = hs * SEG;
    for (int i = tid; i < PER4; i += 256) {
        float4 v = p[i];
        int ei = base_elem + i * 4;
        float sv[4] = {v.x, v.y, v.z, v.w};
        #pragma unroll
        for (int c = 0; c < 4; ++c) {
            float s2 = sv[c];
            if (s2 >= SCORE_THR) {
                unsigned fb = __float_as_uint(s2);
                unsigned pos = atomicAdd(&cur[score_bin(fb)], 1u);
                unsigned idx = (unsigned)(ei + c);
                dst[pos] = ((unsigned long long)fb << 32) | (unsigned)(~idx);
            }
        }
    }
}

// K2: one block per batch, ALL-LDS after the gathers.
union UA {
    unsigned long long keysR[CAP];                   // 32 KB  (phases C-F)
    struct {                                         // 27 KB  (phases H+)
        unsigned rowcnt[W];
        unsigned rowstart[W + 1];
        unsigned rowcur[W];
        unsigned rowlist[CAP];                       // (x<<12)|rank
        unsigned char state[TOPK];                   // 0=und 1=kept 2=dead
        int changed;
    } nb;
};

__global__ __launch_bounds__(1024) void finish_kernel(
    const float* __restrict__ dev4, const unsigned* __restrict__ hpart32,
    const unsigned long long* __restrict__ bucket, float* __restrict__ out)
{
    __shared__ unsigned p2[NBINS + 1];     // coarse gpfx (A-C), then fine pfx (E+)
    __shared__ unsigned h2[NBINS];         // fine hist, then fine cursors
    __shared__ unsigned csum[1024];
    __shared__ unsigned long long keysS[CAP];   // fine-bin-grouped keys
    __shared__ UA u;
    __shared__ unsigned sj[SUBS];
    __shared__ unsigned basej[SUBS + 1];
    __shared__ unsigned sbstar, sshift, sfbase;
    const int b = blockIdx.x, tid = threadIdx.x;

    // ---- A: reduce 32 partial hists -> coarse suffix counts; find bstar ----
    unsigned c0 = 0, c1 = 0;
    for (int j = 0; j < SUBS; ++j) {
        unsigned pr = hpart32[(size_t)(b * SUBS + j) * (NBINS / 2) + tid];
        c0 += pr & 0xFFFFu;
        c1 += pr >> 16;
    }
    csum[tid] = c0 + c1;
    if (tid == 0) sbstar = 0;
    __syncthreads();
    for (int off = 1; off < 1024; off <<= 1) {
        unsigned v = (tid + off < 1024) ? csum[tid + off] : 0u;
        __syncthreads();
        csum[tid] += v;
        __syncthreads();
    }
    p2[2 * tid] = csum[tid];
    p2[2 * tid + 1] = csum[tid] - c0;
    if (tid == 0) p2[NBINS] = 0;
    __syncthreads();
    {
        int B0 = 2 * tid, B1 = 2 * tid + 1;
        if (p2[B0] >= TOPK && p2[B0 + 1] < TOPK) sbstar = (unsigned)B0;
        if (p2[B1] >= TOPK && p2[B1 + 1] < TOPK) sbstar = (unsigned)B1;
    }
    __syncthreads();
    const unsigned bstar = sbstar;
    const unsigned Tfull = p2[bstar];
    const unsigned T = Tfull < CAP ? Tfull : CAP;
    const int nvalid = (int)(T < TOPK ? T : TOPK);

    // ---- B: per-source-block prefix sizes (bins>=bstar are segment prefixes) ----
    {
        int j = tid >> 5, lane = tid & 31;
        unsigned s = 0;
        const unsigned* hp = hpart32 + (size_t)(b * SUBS + j) * (NBINS / 2);
        for (unsigned pi = (bstar >> 1) + lane; pi < NBINS / 2; pi += 32) {
            unsigned pr = hp[pi];
            unsigned lo = pr & 0xFFFFu, hi = pr >> 16;
            s += ((2 * pi) >= bstar ? lo : 0u) + hi;
        }
        #pragma unroll
        for (int d = 16; d > 0; d >>= 1) s += __shfl_down(s, d, 32);
        if (lane == 0) sj[j] = s;
    }
    __syncthreads();
    if (tid == 0) {
        unsigned acc = 0;
        for (int j = 0; j < SUBS; ++j) { basej[j] = acc; acc += sj[j]; }
        basej[SUBS] = acc;
        // D: fine-bin parameters
        unsigned nb2 = 0x800u - bstar;
        unsigned sft = 0;
        while (((nb2 << 12) >> sft) > (unsigned)NBINS) ++sft;
        sshift = sft;
        sfbase = (0x3F000u + bstar) << 12;   // exponent-126 binade: fb>>12 = 0x3F000+bin
    }
    __syncthreads();
    const unsigned shift = sshift, fbase = sfbase;

    // ---- C: gather survivor keys (raw order) ----
    for (unsigned i = tid; i < T; i += 1024) {
        int lo = 0, hi = SUBS - 1;
        while (lo < hi) { int mid = (lo + hi + 1) >> 1; if (basej[mid] <= i) lo = mid; else hi = mid - 1; }
        u.keysR[i] = bucket[(size_t)(b * SUBS + lo) * SEG + (i - basej[lo])];
    }
    for (int i = tid; i < NBINS; i += 1024) h2[i] = 0;
    __syncthreads();

    // ---- E: fine histogram + suffix scan ----
    for (unsigned i = tid; i < T; i += 1024) {
        unsigned fb = (unsigned)(u.keysR[i] >> 32);
        atomicAdd(&h2[(fb - fbase) >> shift], 1u);
    }
    __syncthreads();
    {
        unsigned d0 = h2[2 * tid], d1 = h2[2 * tid + 1];
        csum[tid] = d0 + d1;
        __syncthreads();
        for (int off = 1; off < 1024; off <<= 1) {
            unsigned v = (tid + off < 1024) ? csum[tid + off] : 0u;
            __syncthreads();
            csum[tid] += v;
            __syncthreads();
        }
        p2[2 * tid] = csum[tid];
        p2[2 * tid + 1] = csum[tid] - d0;
        if (tid == 0) p2[NBINS] = 0;
    }
    __syncthreads();
    for (int i = tid; i < NBINS; i += 1024) h2[i] = p2[i + 1];   // cursors
    __syncthreads();

    // ---- F: scatter into fine-bin-grouped keysS ----
    for (unsigned i = tid; i < T; i += 1024) {
        unsigned long long key = u.keysR[i];
        unsigned fb = (unsigned)(key >> 32);
        unsigned pos = atomicAdd(&h2[(fb - fbase) >> shift], 1u);
        keysS[pos] = key;
    }
    __syncthreads();

    // ---- G: exact rank (tiny fine-bin segments; unique keys -> jax order) ----
    unsigned myr[4], myidx[4];
    unsigned long long mykey[4];
    #pragma unroll
    for (int q = 0; q < 4; ++q) {
        unsigned pos = tid + q * 1024;
        myr[q] = 0xFFFFFFFFu;
        mykey[q] = 0; myidx[q] = 0;
        if (pos < T) {
            unsigned long long key = keysS[pos];
            unsigned fb = (unsigned)(key >> 32);
            unsigned B = (fb - fbase) >> shift;
            unsigned st = p2[B + 1], en = p2[B];
            unsigned r = st;
            for (unsigned i = st; i < en; ++i) r += (keysS[i] > key);
            if (r < (unsigned)nvalid) {
                myr[q] = r; mykey[q] = key; myidx[q] = ~(unsigned)key;
            }
        }
    }
    __syncthreads();   // keysR no longer needed; union switches to nb

    // ---- H: row-bucket the kept boxes: rowlist sorted by row ----
    for (int i = tid; i < W; i += 1024) u.nb.rowcnt[i] = 0;
    for (int i = tid; i < TOPK; i += 1024) u.nb.state[i] = 2;
    __syncthreads();
    #pragma unroll
    for (int q = 0; q < 4; ++q)
        if (myr[q] != 0xFFFFFFFFu) atomicAdd(&u.nb.rowcnt[myidx[q] / W], 1u);
    __syncthreads();
    {
        unsigned c = (tid < W) ? u.nb.rowcnt[tid] : 0u;
        csum[tid] = c;
        __syncthreads();
        for (int off = 1; off < 1024; off <<= 1) {
            unsigned v = (tid >= off) ? csum[tid - off] : 0u;
            __syncthreads();
            csum[tid] += v;
            __syncthreads();
        }
        if (tid < W) { u.nb.rowstart[tid + 1] = csum[tid]; u.nb.rowcur[tid] = csum[tid] - c; }
        if (tid == 0) u.nb.rowstart[0] = 0;
    }
    __syncthreads();
    #pragma unroll
    for (int q = 0; q < 4; ++q)
        if (myr[q] != 0xFFFFFFFFu) {
            unsigned y = myidx[q] / W, x = myidx[q] % W;
            unsigned pos = atomicAdd(&u.nb.rowcur[y], 1u);
            u.nb.rowlist[pos] = (x << 12) | myr[q];
        }
    __syncthreads();

    // ---- I: neighbor discovery in LDS (rows y-1..y+1, |dx|<=1, earlier rank) ----
    unsigned long long l0[4] = {0,0,0,0}, l1[4] = {0,0,0,0};
    int nc[4] = {0,0,0,0};
    #pragma unroll
    for (int q = 0; q < 4; ++q) {
        if (myr[q] != 0xFFFFFFFFu) {
            unsigned y = myidx[q] / W, x = myidx[q] % W;
            int c2 = 0;
            unsigned long long a0 = 0, a1 = 0;
            #pragma unroll
            for (int dy = -1; dy <= 1; ++dy) {
                unsigned yy = y + (unsigned)dy;
                if (yy < (unsigned)W) {
                    unsigned s0 = u.nb.rowstart[yy], e0 = u.nb.rowstart[yy + 1];
                    for (unsigned i = s0; i < e0; ++i) {
                        unsigned e = u.nb.rowlist[i];
                        unsigned xx = e >> 12, rr = e & 0xFFFu;
                        if ((xx - x + 1u) <= 2u && rr < myr[q]) {
                            if (c2 < 4)      a0 |= (unsigned long long)rr << (c2 * 16);
                            else if (c2 < 8) a1 |= (unsigned long long)rr << ((c2 - 4) * 16);
                            c2++;
                        }
                    }
                }
            }
            if (c2 > 8) c2 = 8;
            l0[q] = a0; l1[q] = a1; nc[q] = c2;
            u.nb.state[myr[q]] = (c2 == 0) ? 1 : 0;
        }
    }
    __syncthreads();

    // ---- J: monotone fixpoint == sequential greedy NMS ----
    while (true) {
        if (tid == 0) u.nb.changed = 0;
        __syncthreads();
        bool ch = false;
        #pragma unroll
        for (int q = 0; q < 4; ++q) {
            if (myr[q] != 0xFFFFFFFFu && u.nb.state[myr[q]] == 0) {
                bool anyK = false, anyU = false;
                int c = nc[q];
                #pragma unroll
                for (int l = 0; l < 8; ++l) {
                    if (l < c) {
                        unsigned rr = (l < 4)
                            ? (unsigned)((l0[q] >> (l * 16)) & 0xFFFFu)
                            : (unsigned)((l1[q] >> ((l - 4) * 16)) & 0xFFFFu);
                        unsigned char st = u.nb.state[rr];
                        anyK |= (st == 1);
                        anyU |= (st == 0);
                    }
                }
                if (anyK)      { u.nb.state[myr[q]] = 2; ch = true; }
                else if (!anyU){ u.nb.state[myr[q]] = 1; ch = true; }
            }
        }
        if (ch) u.nb.changed = 1;
        __syncthreads();
        if (u.nb.changed == 0) break;
        __syncthreads();
    }

    // ---- K: refine + write ----
    for (int r = nvalid + tid; r < TOPK; r += 1024) {
        float* op = out + ((size_t)b * TOPK + r) * 5;
        op[0] = 0.f; op[1] = 0.f; op[2] = 0.f; op[3] = 0.f; op[4] = 0.f;
    }
    #pragma unroll
    for (int q = 0; q < 4; ++q) {
        if (myr[q] != 0xFFFFFFFFu) {
            unsigned r = myr[q];
            float o0 = 0.f, o1 = 0.f, o2 = 0.f, o3 = 0.f, o4 = 0.f;
            if (u.nb.state[r] == 1) {
                unsigned idx = myidx[q];
                float sc = __uint_as_float((unsigned)(mykey[q] >> 32));
                int y = (int)(idx / W), x = (int)(idx % W);
                const float4 d = ((const float4*)dev4)[(size_t)b * NPROB + idx];
                float b0 = (float)(4 * y + 2);
                float b1 = (float)(4 * x + 2);
                float b2 = (float)(4 * y + 24);
                float b3 = (float)(4 * x + 24);
                float r0 = b0 + d.x * 22.0f;
                float r1 = b1 + d.y * 22.0f;
                float r2 = b2 + d.z * 22.0f;
                float r3 = b3 + d.w * 22.0f;
                float rh = r2 - r0, rw = r3 - r1;
                float len = fmaxf(rh, rw);
                float c0v = r0 + rh * 0.5f, c1v = r1 + rw * 0.5f;
                float u0 = c0v - 0.5f * len, u1 = c1v - 0.5f * len;
                float v0 = u0 + len, v1 = u1 + len;
                o0 = fminf(fmaxf(u0, 1.0f), 3095.0f);
                o1 = fminf(fmaxf(u1, 1.0f), 3095.0f);
                o2 = fminf(fmaxf(v0, 1.0f), 3095.0f);
                o3 = fminf(fmaxf(v1, 1.0f), 3095.0f);
                o4 = sc;
            }
            float* op = out + ((size_t)b * TOPK + r) * 5;
            op[0] = o0; op[1] = o1; op[2] = o2; op[3] = o3; op[4] = o4;
        }
    }
}

extern "C" void kernel_launch(void* const* d_in, const int* in_sizes, int n_in,
                              void* d_out, int out_size, void* d_ws, size_t ws_size,
                              hipStream_t stream) {
    (void)in_sizes; (void)n_in; (void)out_size;
    if (ws_size < (size_t)WS_TOTAL) return;

    const float* probs = (const float*)d_in[0];
    const float* devs  = (const float*)d_in[1];
    float* out = (float*)d_out;
    char* ws = (char*)d_ws;

    unsigned* hpart32 = (unsigned*)(ws + HPART_OFF);
    unsigned long long* bucket = (unsigned long long*)(ws + BUCKET_OFF);

    scatter_kernel<<<dim3(SUBS, NB), 256, 0, stream>>>(probs, hpart32, bucket);
    finish_kernel<<<NB, 1024, 0, stream>>>(devs, hpart32, bucket, out);
}

// Round 12
// 43.532 us; speedup vs baseline: 2.8804x; 1.1176x over previous
//
#include <hip/hip_runtime.h>
#include <stdint.h>

#define W 768
#define NPROB (768*768)
#define NB 8
#define NBINS 2048           // coarse bin = (fb>>12)&0x7FF within the [0.5,1) binade
#define CAP 4096
#define TOPK 2048
#define SCORE_THR 0.6f
#define SUBS 32              // K1 blocks per batch
#define SEG (NPROB/SUBS)     // 18432 elems per K1 block
#define PER4 (SEG/4)         // 4608 float4 per K1 block

// ws layout (bytes). NOTHING needs pre-init: bucket/hpart written by K1
// before K2 reads (stream order).
#define HPART_OFF  0
#define HPART_BYTES (NB*SUBS*NBINS*2)           // 1,048,576 (u16 pairs in u32)
#define BUCKET_OFF (HPART_OFF + HPART_BYTES)
#define BUCKET_BYTES (NB*(size_t)SUBS*SEG*8)    // 37,748,736
#define WS_TOTAL   (BUCKET_OFF + BUCKET_BYTES)

// valid scores in [0.6,1.0) -> exponent-126 binade; float bits monotone.
__device__ __forceinline__ unsigned score_bin(unsigned fb) {
    return (fb >> 12) & 0x7FFu;
}

// K1: per-block counting sort with SAFE local prune.
// B0 = max{B : local pfx[B] >= TOPK}; global pfx >= local pfx => bstar >= B0,
// so bins < B0 can never be in the global top-K -> skip scattering them.
__global__ __launch_bounds__(256) void scatter_kernel(
    const float* __restrict__ probs, unsigned* __restrict__ hpart32,
    unsigned long long* __restrict__ bucket)
{
    __shared__ unsigned lh[NBINS];
    __shared__ unsigned cur[NBINS];
    __shared__ unsigned csum[256];
    __shared__ unsigned sB0;
    const int b = blockIdx.y, hs = blockIdx.x, tid = threadIdx.x;

    for (int i = tid; i < NBINS; i += 256) lh[i] = 0;
    if (tid == 0) sB0 = 0;
    __syncthreads();
    const float4* p = (const float4*)(probs + (size_t)b * NPROB) + (size_t)hs * PER4;
    for (int i = tid; i < PER4; i += 256) {
        float4 v = p[i];
        if (v.x >= SCORE_THR) atomicAdd(&lh[score_bin(__float_as_uint(v.x))], 1u);
        if (v.y >= SCORE_THR) atomicAdd(&lh[score_bin(__float_as_uint(v.y))], 1u);
        if (v.z >= SCORE_THR) atomicAdd(&lh[score_bin(__float_as_uint(v.z))], 1u);
        if (v.w >= SCORE_THR) atomicAdd(&lh[score_bin(__float_as_uint(v.w))], 1u);
    }
    __syncthreads();
    {
        unsigned* gh = hpart32 + (size_t)(b * SUBS + hs) * (NBINS / 2);
        for (int i = tid; i < NBINS / 2; i += 256)
            gh[i] = (lh[2 * i] & 0xFFFFu) | (lh[2 * i + 1] << 16);
    }
    unsigned s = 0;
    #pragma unroll
    for (int i = 0; i < 8; ++i) s += lh[tid * 8 + i];
    csum[tid] = s;
    __syncthreads();
    for (int off = 1; off < 256; off <<= 1) {
        unsigned v = (tid + off < 256) ? csum[tid + off] : 0u;
        __syncthreads();
        csum[tid] += v;
        __syncthreads();
    }
    unsigned run = csum[tid];               // suffix incl bin 8*tid
    unsigned localB0 = 0;
    #pragma unroll
    for (int i = 0; i < 8; ++i) {
        unsigned B = tid * 8 + i;
        if (run >= TOPK) localB0 = B;       // pfx decreasing: last qualifying B is max
        cur[B] = run - lh[B];
        run -= lh[B];
    }
    if (localB0) atomicMax(&sB0, localB0);
    __syncthreads();
    // scatter threshold as one float compare (bin >= B0 && score >= 0.6)
    float thrF = __uint_as_float(0x3F000000u | (sB0 << 12));
    if (thrF < SCORE_THR) thrF = SCORE_THR;

    unsigned long long* dst = bucket + (size_t)(b * SUBS + hs) * SEG;
    int base_elem = hs * SEG;
    for (int i = tid; i < PER4; i += 256) {
        float4 v = p[i];
        int ei = base_elem + i * 4;
        float sv[4] = {v.x, v.y, v.z, v.w};
        #pragma unroll
        for (int c = 0; c < 4; ++c) {
            float s2 = sv[c];
            if (s2 >= thrF) {
                unsigned fb = __float_as_uint(s2);
                unsigned pos = atomicAdd(&cur[score_bin(fb)], 1u);
                unsigned idx = (unsigned)(ei + c);
                dst[pos] = ((unsigned long long)fb << 32) | (unsigned)(~idx);
            }
        }
    }
}

// ---- wave-shuffle scans for 1024 threads (1 barrier each direction) ----
__device__ __forceinline__ unsigned suffix_scan1024(unsigned v, unsigned* wtot, int tid) {
    int lane = tid & 63, wv = tid >> 6;
    unsigned s = v;
    #pragma unroll
    for (int d = 1; d < 64; d <<= 1) {
        unsigned t = __shfl_down(s, d, 64);
        if (lane + d < 64) s += t;
    }
    if (lane == 0) wtot[wv] = s;
    __syncthreads();
    if (tid < 16) {
        unsigned t = wtot[tid];
        #pragma unroll
        for (int d = 1; d < 16; d <<= 1) {
            unsigned u2 = __shfl_down(t, d, 64);
            if (tid + d < 16) t += u2;
        }
        wtot[tid] = t;
    }
    __syncthreads();
    unsigned higher = (wv + 1 < 16) ? wtot[wv + 1] : 0u;
    return s + higher;
}
__device__ __forceinline__ unsigned prefix_scan1024(unsigned v, unsigned* wtot, int tid) {
    int lane = tid & 63, wv = tid >> 6;
    unsigned s = v;
    #pragma unroll
    for (int d = 1; d < 64; d <<= 1) {
        unsigned t = __shfl_up(s, d, 64);
        if (lane >= d) s += t;
    }
    if (lane == 63) wtot[wv] = s;
    __syncthreads();
    if (tid < 16) {
        unsigned t = wtot[tid];
        #pragma unroll
        for (int d = 1; d < 16; d <<= 1) {
            unsigned u2 = __shfl_up(t, d, 64);
            if (tid >= d) t += u2;
        }
        wtot[tid] = t;
    }
    __syncthreads();
    unsigned lower = (wv > 0) ? wtot[wv - 1] : 0u;
    return s + lower;
}

// K2: one block per batch, ALL-LDS after the gathers. (r11 structure, fast scans)
union UA {
    unsigned long long keysR[CAP];                   // 32 KB  (phases C-F)
    struct {                                         // 27 KB  (phases H+)
        unsigned rowcnt[W];
        unsigned rowstart[W + 1];
        unsigned rowcur[W];
        unsigned rowlist[CAP];                       // (x<<12)|rank
        unsigned char state[TOPK];
        int changed;
    } nb;
};

__global__ __launch_bounds__(1024) void finish_kernel(
    const float* __restrict__ dev4, const unsigned* __restrict__ hpart32,
    const unsigned long long* __restrict__ bucket, float* __restrict__ out)
{
    __shared__ unsigned p2[NBINS + 1];
    __shared__ unsigned h2[NBINS];
    __shared__ unsigned wtot[17];
    __shared__ unsigned long long keysS[CAP];
    __shared__ UA u;
    __shared__ unsigned sj[SUBS];
    __shared__ unsigned basej[SUBS + 1];
    __shared__ unsigned sbstar, sshift, sfbase;
    const int b = blockIdx.x, tid = threadIdx.x;

    // ---- A: reduce 32 partial hists -> coarse suffix counts; find bstar ----
    unsigned c0 = 0, c1 = 0;
    for (int j = 0; j < SUBS; ++j) {
        unsigned pr = hpart32[(size_t)(b * SUBS + j) * (NBINS / 2) + tid];
        c0 += pr & 0xFFFFu;
        c1 += pr >> 16;
    }
    if (tid == 0) sbstar = 0;
    unsigned suf = suffix_scan1024(c0 + c1, wtot, tid);
    p2[2 * tid] = suf;
    p2[2 * tid + 1] = suf - c0;
    if (tid == 0) p2[NBINS] = 0;
    __syncthreads();
    {
        int B0 = 2 * tid, B1 = 2 * tid + 1;
        if (p2[B0] >= TOPK && p2[B0 + 1] < TOPK) sbstar = (unsigned)B0;
        if (p2[B1] >= TOPK && p2[B1 + 1] < TOPK) sbstar = (unsigned)B1;
    }
    __syncthreads();
    const unsigned bstar = sbstar;
    const unsigned Tfull = p2[bstar];
    const unsigned T = Tfull < CAP ? Tfull : CAP;
    const int nvalid = (int)(T < TOPK ? T : TOPK);

    // ---- B: per-source-block survivor counts (bins >= bstar) ----
    {
        int j = tid >> 5, lane = tid & 31;
        unsigned s = 0;
        const unsigned* hp = hpart32 + (size_t)(b * SUBS + j) * (NBINS / 2);
        for (unsigned pi = (bstar >> 1) + lane; pi < NBINS / 2; pi += 32) {
            unsigned pr = hp[pi];
            unsigned lo = pr & 0xFFFFu, hi = pr >> 16;
            s += ((2 * pi) >= bstar ? lo : 0u) + hi;
        }
        #pragma unroll
        for (int d = 16; d > 0; d >>= 1) s += __shfl_down(s, d, 32);
        if (lane == 0) sj[j] = s;
    }
    __syncthreads();
    if (tid == 0) {
        unsigned acc = 0;
        for (int j = 0; j < SUBS; ++j) { basej[j] = acc; acc += sj[j]; }
        basej[SUBS] = acc;
        unsigned nb2 = 0x800u - bstar;
        unsigned sft = 0;
        while (((nb2 << 12) >> sft) > (unsigned)NBINS) ++sft;
        sshift = sft;
        sfbase = (0x3F000u + bstar) << 12;
    }
    __syncthreads();
    const unsigned shift = sshift, fbase = sfbase;

    // ---- C: gather survivor keys ----
    for (unsigned i = tid; i < T; i += 1024) {
        int lo = 0, hi = SUBS - 1;
        while (lo < hi) { int mid = (lo + hi + 1) >> 1; if (basej[mid] <= i) lo = mid; else hi = mid - 1; }
        u.keysR[i] = bucket[(size_t)(b * SUBS + lo) * SEG + (i - basej[lo])];
    }
    for (int i = tid; i < NBINS; i += 1024) h2[i] = 0;
    __syncthreads();

    // ---- E: fine histogram + suffix scan ----
    for (unsigned i = tid; i < T; i += 1024) {
        unsigned fb = (unsigned)(u.keysR[i] >> 32);
        atomicAdd(&h2[(fb - fbase) >> shift], 1u);
    }
    __syncthreads();
    {
        unsigned d0 = h2[2 * tid], d1 = h2[2 * tid + 1];
        unsigned sf = suffix_scan1024(d0 + d1, wtot, tid);
        p2[2 * tid] = sf;
        p2[2 * tid + 1] = sf - d0;
        if (tid == 0) p2[NBINS] = 0;
    }
    __syncthreads();
    for (int i = tid; i < NBINS; i += 1024) h2[i] = p2[i + 1];   // cursors
    __syncthreads();

    // ---- F: scatter into fine-bin-grouped keysS ----
    for (unsigned i = tid; i < T; i += 1024) {
        unsigned long long key = u.keysR[i];
        unsigned fb = (unsigned)(key >> 32);
        unsigned pos = atomicAdd(&h2[(fb - fbase) >> shift], 1u);
        keysS[pos] = key;
    }
    __syncthreads();

    // ---- G: exact rank (tiny fine-bin segments; unique keys -> jax order) ----
    unsigned myr[4], myidx[4];
    unsigned long long mykey[4];
    #pragma unroll
    for (int q = 0; q < 4; ++q) {
        unsigned pos = tid + q * 1024;
        myr[q] = 0xFFFFFFFFu;
        mykey[q] = 0; myidx[q] = 0;
        if (pos < T) {
            unsigned long long key = keysS[pos];
            unsigned fb = (unsigned)(key >> 32);
            unsigned B = (fb - fbase) >> shift;
            unsigned st = p2[B + 1], en = p2[B];
            unsigned r = st;
            for (unsigned i = st; i < en; ++i) r += (keysS[i] > key);
            if (r < (unsigned)nvalid) {
                myr[q] = r; mykey[q] = key; myidx[q] = ~(unsigned)key;
            }
        }
    }
    __syncthreads();   // keysR dead; union switches to nb

    // ---- H: row-bucket kept boxes ----
    for (int i = tid; i < W; i += 1024) u.nb.rowcnt[i] = 0;
    for (int i = tid; i < TOPK; i += 1024) u.nb.state[i] = 2;
    __syncthreads();
    #pragma unroll
    for (int q = 0; q < 4; ++q)
        if (myr[q] != 0xFFFFFFFFu) atomicAdd(&u.nb.rowcnt[myidx[q] / W], 1u);
    __syncthreads();
    {
        unsigned c = (tid < W) ? u.nb.rowcnt[tid] : 0u;
        unsigned incl = prefix_scan1024(c, wtot, tid);
        if (tid < W) { u.nb.rowstart[tid + 1] = incl; u.nb.rowcur[tid] = incl - c; }
        if (tid == 0) u.nb.rowstart[0] = 0;
    }
    __syncthreads();
    #pragma unroll
    for (int q = 0; q < 4; ++q)
        if (myr[q] != 0xFFFFFFFFu) {
            unsigned y = myidx[q] / W, x = myidx[q] % W;
            unsigned pos = atomicAdd(&u.nb.rowcur[y], 1u);
            u.nb.rowlist[pos] = (x << 12) | myr[q];
        }
    __syncthreads();

    // ---- I: neighbor discovery in LDS (rows y-1..y+1, |dx|<=1, earlier rank) ----
    unsigned long long l0[4] = {0,0,0,0}, l1[4] = {0,0,0,0};
    int nc[4] = {0,0,0,0};
    #pragma unroll
    for (int q = 0; q < 4; ++q) {
        if (myr[q] != 0xFFFFFFFFu) {
            unsigned y = myidx[q] / W, x = myidx[q] % W;
            int c2 = 0;
            unsigned long long a0 = 0, a1 = 0;
            #pragma unroll
            for (int dy = -1; dy <= 1; ++dy) {
                unsigned yy = y + (unsigned)dy;
                if (yy < (unsigned)W) {
                    unsigned s0 = u.nb.rowstart[yy], e0 = u.nb.rowstart[yy + 1];
                    for (unsigned i = s0; i < e0; ++i) {
                        unsigned e = u.nb.rowlist[i];
                        unsigned xx = e >> 12, rr = e & 0xFFFu;
                        if ((xx - x + 1u) <= 2u && rr < myr[q]) {
                            if (c2 < 4)      a0 |= (unsigned long long)rr << (c2 * 16);
                            else if (c2 < 8) a1 |= (unsigned long long)rr << ((c2 - 4) * 16);
                            c2++;
                        }
                    }
                }
            }
            if (c2 > 8) c2 = 8;
            l0[q] = a0; l1[q] = a1; nc[q] = c2;
            u.nb.state[myr[q]] = (c2 == 0) ? 1 : 0;
        }
    }
    __syncthreads();

    // ---- J: monotone fixpoint == sequential greedy NMS ----
    while (true) {
        if (tid == 0) u.nb.changed = 0;
        __syncthreads();
        bool ch = false;
        #pragma unroll
        for (int q = 0; q < 4; ++q) {
            if (myr[q] != 0xFFFFFFFFu && u.nb.state[myr[q]] == 0) {
                bool anyK = false, anyU = false;
                int c = nc[q];
                #pragma unroll
                for (int l = 0; l < 8; ++l) {
                    if (l < c) {
                        unsigned rr = (l < 4)
                            ? (unsigned)((l0[q] >> (l * 16)) & 0xFFFFu)
                            : (unsigned)((l1[q] >> ((l - 4) * 16)) & 0xFFFFu);
                        unsigned char st = u.nb.state[rr];
                        anyK |= (st == 1);
                        anyU |= (st == 0);
                    }
                }
                if (anyK)      { u.nb.state[myr[q]] = 2; ch = true; }
                else if (!anyU){ u.nb.state[myr[q]] = 1; ch = true; }
            }
        }
        if (ch) u.nb.changed = 1;
        __syncthreads();
        if (u.nb.changed == 0) break;
        __syncthreads();
    }

    // ---- K: refine + write ----
    for (int r = nvalid + tid; r < TOPK; r += 1024) {
        float* op = out + ((size_t)b * TOPK + r) * 5;
        op[0] = 0.f; op[1] = 0.f; op[2] = 0.f; op[3] = 0.f; op[4] = 0.f;
    }
    #pragma unroll
    for (int q = 0; q < 4; ++q) {
        if (myr[q] != 0xFFFFFFFFu) {
            unsigned r = myr[q];
            float o0 = 0.f, o1 = 0.f, o2 = 0.f, o3 = 0.f, o4 = 0.f;
            if (u.nb.state[r] == 1) {
                unsigned idx = myidx[q];
                float sc = __uint_as_float((unsigned)(mykey[q] >> 32));
                int y = (int)(idx / W), x = (int)(idx % W);
                const float4 d = ((const float4*)dev4)[(size_t)b * NPROB + idx];
                float b0 = (float)(4 * y + 2);
                float b1 = (float)(4 * x + 2);
                float b2 = (float)(4 * y + 24);
                float b3 = (float)(4 * x + 24);
                float r0 = b0 + d.x * 22.0f;
                float r1 = b1 + d.y * 22.0f;
                float r2 = b2 + d.z * 22.0f;
                float r3 = b3 + d.w * 22.0f;
                float rh = r2 - r0, rw = r3 - r1;
                float len = fmaxf(rh, rw);
                float c0v = r0 + rh * 0.5f, c1v = r1 + rw * 0.5f;
                float u0 = c0v - 0.5f * len, u1 = c1v - 0.5f * len;
                float v0 = u0 + len, v1 = u1 + len;
                o0 = fminf(fmaxf(u0, 1.0f), 3095.0f);
                o1 = fminf(fmaxf(u1, 1.0f), 3095.0f);
                o2 = fminf(fmaxf(v0, 1.0f), 3095.0f);
                o3 = fminf(fmaxf(v1, 1.0f), 3095.0f);
                o4 = sc;
            }
            float* op = out + ((size_t)b * TOPK + r) * 5;
            op[0] = o0; op[1] = o1; op[2] = o2; op[3] = o3; op[4] = o4;
        }
    }
}

extern "C" void kernel_launch(void* const* d_in, const int* in_sizes, int n_in,
                              void* d_out, int out_size, void* d_ws, size_t ws_size,
                              hipStream_t stream) {
    (void)in_sizes; (void)n_in; (void)out_size;
    if (ws_size < (size_t)WS_TOTAL) return;

    const float* probs = (const float*)d_in[0];
    const float* devs  = (const float*)d_in[1];
    float* out = (float*)d_out;
    char* ws = (char*)d_ws;

    unsigned* hpart32 = (unsigned*)(ws + HPART_OFF);
    unsigned long long* bucket = (unsigned long long*)(ws + BUCKET_OFF);

    scatter_kernel<<<dim3(SUBS, NB), 256, 0, stream>>>(probs, hpart32, bucket);
    finish_kernel<<<NB, 1024, 0, stream>>>(devs, hpart32, bucket, out);
}